// Round 11
// baseline (216.898 us; speedup 1.0000x reference)
//
#include <hip/hip_runtime.h>
#include <hip/hip_bf16.h>
#include <cstddef>

// GCN forward: out = A·(relu(A·(X·W1)+b1))·W2 + b2
// NFEAT=512, NHID=128, NCLS=40 hard-wired; N,E from in_sizes.
// CSR (counting sort) -> segment-sum SpMM.
// NEW: X pre-converted to bf16 (xconv streaming pass); gemm1 reads bf16 A,
// pinned to 2 waves/EU (VGPR budget 256) for deep load pipelining; XCD swizzle.

typedef float f32x4 __attribute__((ext_vector_type(4)));
typedef short bf16x8 __attribute__((ext_vector_type(8)));

static __device__ __forceinline__ short f2bf(float f) {
    __hip_bfloat16 b = __float2bfloat16(f);
    return *reinterpret_cast<short*>(&b);
}
static __device__ __forceinline__ float bflo(unsigned u) {
    union { unsigned i; float f; } v; v.i = u << 16; return v.f;
}
static __device__ __forceinline__ float bfhi(unsigned u) {
    union { unsigned i; float f; } v; v.i = u & 0xFFFF0000u; return v.f;
}
static __device__ __forceinline__ unsigned pack2bf(float lo, float hi) {
    unsigned a = (unsigned short)f2bf(lo);
    unsigned b = (unsigned short)f2bf(hi);
    return a | (b << 16);
}

typedef const __attribute__((address_space(1))) void* gas_ptr;
typedef __attribute__((address_space(3))) void* las_ptr;
static __device__ __forceinline__ void gload16(const void* g, void* l) {
    __builtin_amdgcn_global_load_lds((gas_ptr)g, (las_ptr)l, 16, 0, 0);
}

// ---- prep: W1->W1Ts (swizzled bf16 W1T), W2->W2Ts, zero cur[] ----
__global__ __launch_bounds__(256) void prep_kernel(
    const float* __restrict__ W1, short* __restrict__ W1Ts,
    const float* __restrict__ W2, short* __restrict__ W2Ts,
    int* __restrict__ cur, int N)
{
    int idx = blockIdx.x * 256 + threadIdx.x;
    if (idx < 65536) {
        int k = idx >> 7, n = idx & 127;
        int lin = n * 512 + k;
        W1Ts[lin ^ ((n & 7) << 3)] = f2bf(W1[idx]);
    } else if (idx < 65536 + 6144) {
        int i2 = idx - 65536;
        int n = i2 >> 7, k = i2 & 127;
        W2Ts[i2 ^ ((n & 7) << 3)] = (n < 40) ? f2bf(W2[k * 40 + n]) : (short)0;
    } else if (idx < 65536 + 6144 + N) {
        cur[idx - 65536 - 6144] = 0;
    }
}

// ---- xconv: X[N*512] f32 -> Xb bf16 (streaming, 16B stores) ----
__global__ __launch_bounds__(256) void xconv_kernel(
    const float4* __restrict__ X4, uint4* __restrict__ Xb4, int n4out)
{
    for (int i = blockIdx.x * 256 + threadIdx.x; i < n4out; i += gridDim.x * 256) {
        const float4 f0 = X4[2 * i];
        const float4 f1 = X4[2 * i + 1];
        uint4 o;
        o.x = pack2bf(f0.x, f0.y);
        o.y = pack2bf(f0.z, f0.w);
        o.z = pack2bf(f1.x, f1.y);
        o.w = pack2bf(f1.z, f1.w);
        Xb4[i] = o;
    }
}

// ---------------- GEMM1: XW1b[M,128](bf16) = Xb[M,512](bf16) @ W1 ----------------
// 512 thr = 8 waves: 4 row-groups x 2 col-halves; wave = 32r x 64c (2x4 frags).
// Whole W1Ts in LDS (128KB, 1 block/CU). Pinned 2 waves/EU -> 256-VGPR schedule.
__global__
__attribute__((amdgpu_flat_work_group_size(512, 512)))
__attribute__((amdgpu_waves_per_eu(2, 2)))
void gemm1_mfma_kernel(
    const short* __restrict__ Xb, const short* __restrict__ W1Ts,
    short* __restrict__ XW1b, int M, int nwg)
{
    __shared__ __align__(16) short Bs[128 * 512];   // 128 KB, pre-swizzled

    // bijective XCD-aware block swizzle (m204)
    int bid = blockIdx.x;
    {
        const int q = nwg >> 3, r = nwg & 7;
        const int xcd = bid & 7, off = bid >> 3;
        bid = (xcd < r ? xcd * (q + 1) : r * (q + 1) + (xcd - r) * q) + off;
    }

    const int tid = threadIdx.x;
    const int w   = tid >> 6;          // 0..7
    const int l   = tid & 63;
    const int l15 = l & 15;
    const int l4  = l >> 4;
    const int row0 = bid * 128 + (w >> 1) * 32;
    const int col0 = (w & 1) * 64;

    // linear 128KB copy global->LDS (layout already swizzled in global)
    {
        const char* src = (const char*)W1Ts;
        char* dst = (char*)Bs;
#pragma unroll
        for (int i = 0; i < 16; ++i)
            gload16(src + i * 8192 + tid * 16, dst + i * 8192 + tid * 16);
    }

    const int r0 = row0 + l15,      c0 = r0 < M ? r0 : M - 1;
    const int r1 = row0 + 16 + l15, c1 = r1 < M ? r1 : M - 1;
    const short* a0p = Xb + (size_t)c0 * 512 + l4 * 8;
    const short* a1p = Xb + (size_t)c1 * 512 + l4 * 8;
    const int swz = (l15 & 7) << 3;

    f32x4 acc[2][4];
#pragma unroll
    for (int i = 0; i < 2; ++i)
#pragma unroll
        for (int f = 0; f < 4; ++f) acc[i][f] = (f32x4)0.f;

    __syncthreads();

#pragma unroll
    for (int kt = 0; kt < 16; ++kt) {
        const bf16x8 a0 = *(const bf16x8*)(a0p + kt * 32);
        const bf16x8 a1 = *(const bf16x8*)(a1p + kt * 32);

#pragma unroll
        for (int f = 0; f < 4; ++f) {
            const int si = ((col0 + f * 16 + l15) * 512 + kt * 32 + l4 * 8) ^ swz;
            const bf16x8 b = *(const bf16x8*)&Bs[si];
            acc[0][f] = __builtin_amdgcn_mfma_f32_16x16x32_bf16(a0, b, acc[0][f], 0, 0, 0);
            acc[1][f] = __builtin_amdgcn_mfma_f32_16x16x32_bf16(a1, b, acc[1][f], 0, 0, 0);
        }
    }

    // D layout: col = lane&15, row = (lane>>4)*4 + reg
#pragma unroll
    for (int i = 0; i < 2; ++i)
#pragma unroll
        for (int r = 0; r < 4; ++r) {
            const int row = row0 + i * 16 + l4 * 4 + r;
            if (row < M) {
#pragma unroll
                for (int f = 0; f < 4; ++f)
                    XW1b[(size_t)row * 128 + col0 + f * 16 + l15] = f2bf(acc[i][f][r]);
            }
        }
}

// ---------------- CSR build ----------------
__global__ __launch_bounds__(256) void hist_kernel(const int* __restrict__ row,
                                                   int* __restrict__ counts, int E)
{
    int e = blockIdx.x * 256 + threadIdx.x;
    if (e < E) atomicAdd(&counts[row[e]], 1);
}

__global__ __launch_bounds__(256) void scan1_kernel(const int* __restrict__ counts,
                                                    int* __restrict__ excl,
                                                    int* __restrict__ bsum, int N)
{
    __shared__ int s[256];
    const int t = threadIdx.x;
    const int i = blockIdx.x * 256 + t;
    int v = (i < N) ? counts[i] : 0;
    s[t] = v; __syncthreads();
#pragma unroll
    for (int off = 1; off < 256; off <<= 1) {
        int tmp = (t >= off) ? s[t - off] : 0;
        __syncthreads();
        s[t] += tmp;
        __syncthreads();
    }
    if (i < N) excl[i] = s[t] - v;
    if (t == 255) bsum[blockIdx.x] = s[255];
}

__global__ __launch_bounds__(256) void scan2_kernel(int* __restrict__ bsum, int NB)
{
    __shared__ int s[256];
    const int t = threadIdx.x;
    int v = (t < NB) ? bsum[t] : 0;
    s[t] = v; __syncthreads();
#pragma unroll
    for (int off = 1; off < 256; off <<= 1) {
        int tmp = (t >= off) ? s[t - off] : 0;
        __syncthreads();
        s[t] += tmp;
        __syncthreads();
    }
    if (t < NB) bsum[t] = s[t] - v;
}

__global__ __launch_bounds__(256) void scan3_kernel(int* __restrict__ rowptr,
                                                    const int* __restrict__ bsum,
                                                    int* __restrict__ cur, int N, int E)
{
    int i = blockIdx.x * 256 + threadIdx.x;
    if (i < N) {
        int v = rowptr[i] + bsum[blockIdx.x];
        rowptr[i] = v;
        cur[i] = v;
    }
    if (i == 0) rowptr[N] = E;
}

__global__ __launch_bounds__(256) void sortedges_kernel(
    const int* __restrict__ row, const int* __restrict__ col,
    const float* __restrict__ w, int* __restrict__ cur,
    int2* __restrict__ se, int E)
{
    int e = blockIdx.x * 256 + threadIdx.x;
    if (e < E) {
        int r = row[e];
        int pos = atomicAdd(&cur[r], 1);
        se[pos] = make_int2(col[e], __float_as_int(w[e]));
    }
}

// ---- segment1: hb[r] = bf16(relu(b1 + sum_j w_j * xw1b[col_j])) ----
__global__ __launch_bounds__(256) void segment1_kernel(
    const int* __restrict__ rowptr, const int2* __restrict__ se,
    const uint2* __restrict__ x2, const float* __restrict__ b1,
    uint2* __restrict__ hb, int N)
{
    const int w    = threadIdx.x >> 6;
    const int lane = threadIdx.x & 63;
    const int h    = lane >> 5;          // half: which edge of the pair
    const int q    = lane & 31;          // uint2 index in row (feats 4q..4q+3)
    const int r = blockIdx.x * 4 + w;
    if (r >= N) return;

    float4 acc = make_float4(0.f, 0.f, 0.f, 0.f);
    if (h == 0) acc = *(const float4*)(b1 + 4 * q);

    int j = rowptr[r];
    const int end = rowptr[r + 1];
    for (; j + 3 < end; j += 4) {
        const int2 ea = se[j + h];
        const int2 eb = se[j + 2 + h];
        const uint2 ua = x2[(size_t)ea.x * 32 + q];
        const uint2 ub = x2[(size_t)eb.x * 32 + q];
        const float wa = __int_as_float(ea.y), wb = __int_as_float(eb.y);
        acc.x = fmaf(wa, bflo(ua.x), acc.x); acc.y = fmaf(wa, bfhi(ua.x), acc.y);
        acc.z = fmaf(wa, bflo(ua.y), acc.z); acc.w = fmaf(wa, bfhi(ua.y), acc.w);
        acc.x = fmaf(wb, bflo(ub.x), acc.x); acc.y = fmaf(wb, bfhi(ub.x), acc.y);
        acc.z = fmaf(wb, bflo(ub.y), acc.z); acc.w = fmaf(wb, bfhi(ub.y), acc.w);
    }
    for (; j < end; j += 2) {
        const int idx = j + h;
        const int ic  = idx < end ? idx : end - 1;
        const int2 e  = se[ic];
        const float wt = idx < end ? __int_as_float(e.y) : 0.f;
        const uint2 u = x2[(size_t)e.x * 32 + q];
        acc.x = fmaf(wt, bflo(u.x), acc.x); acc.y = fmaf(wt, bfhi(u.x), acc.y);
        acc.z = fmaf(wt, bflo(u.y), acc.z); acc.w = fmaf(wt, bfhi(u.y), acc.w);
    }
    acc.x += __shfl_xor(acc.x, 32);
    acc.y += __shfl_xor(acc.y, 32);
    acc.z += __shfl_xor(acc.z, 32);
    acc.w += __shfl_xor(acc.w, 32);
    if (h == 0) {
        const unsigned p0 = pack2bf(fmaxf(acc.x, 0.f), fmaxf(acc.y, 0.f));
        const unsigned p1 = pack2bf(fmaxf(acc.z, 0.f), fmaxf(acc.w, 0.f));
        hb[(size_t)r * 32 + q] = make_uint2(p0, p1);
    }
}

// ---------------- GEMM2: Yb[M,40](bf16) = hb[M,128](bf16) @ W2 ----------------
__global__ __launch_bounds__(256) void gemm2_mfma_kernel(
    const short* __restrict__ hb, const short* __restrict__ W2Ts,
    unsigned short* __restrict__ Yb, int M)
{
    __shared__ __align__(16) short Ws[48 * 128];   // 12 KB, pre-swizzled

    const int tid = threadIdx.x;
    const int w   = tid >> 6;
    const int l   = tid & 63;
    const int l15 = l & 15;
    const int l4  = l >> 4;
    const int row0 = blockIdx.x * 64 + w * 16;

    {
        const char* src = (const char*)W2Ts;
        char* dst = (char*)Ws;
#pragma unroll
        for (int i = 0; i < 3; ++i)
            gload16(src + i * 4096 + tid * 16, dst + i * 4096 + tid * 16);
    }
    __syncthreads();

    f32x4 acc[3];
#pragma unroll
    for (int f = 0; f < 3; ++f) acc[f] = (f32x4)0.f;

    const int rr = row0 + l15;
    const int cr = rr < M ? rr : M - 1;
    const short* hp = hb + (size_t)cr * 128 + l4 * 8;
    const int swz = (l15 & 7) << 3;

#pragma unroll
    for (int kt = 0; kt < 4; ++kt) {
        const bf16x8 a = *(const bf16x8*)(hp + kt * 32);
#pragma unroll
        for (int f = 0; f < 3; ++f) {
            const int si = ((f * 16 + l15) * 128 + kt * 32 + l4 * 8) ^ swz;
            const bf16x8 b = *(const bf16x8*)&Ws[si];
            acc[f] = __builtin_amdgcn_mfma_f32_16x16x32_bf16(a, b, acc[f], 0, 0, 0);
        }
    }

#pragma unroll
    for (int r = 0; r < 4; ++r) {
        const int row = row0 + l4 * 4 + r;
        if (row < M) {
#pragma unroll
            for (int f = 0; f < 3; ++f) {
                const int col = f * 16 + l15;
                if (col < 40)
                    Yb[(size_t)row * 40 + col] = (unsigned short)f2bf(acc[f][r]);
            }
        }
    }
}

// ---- segment2: out[r] = b2 + sum_j w_j * hw2b[col_j]  (3 edges/wave, x2 unroll) ----
__global__ __launch_bounds__(256) void segment2_kernel(
    const int* __restrict__ rowptr, const int2* __restrict__ se,
    const unsigned* __restrict__ hw2, const float* __restrict__ b2,
    float* __restrict__ out, int N)
{
    const int w    = threadIdx.x >> 6;
    const int lane = threadIdx.x & 63;
    const int s    = lane < 20 ? 0 : (lane < 40 ? 1 : 2);
    const int fl   = lane - s * 20;          // 0..19 (lanes 60-63 discarded)
    const int r = blockIdx.x * 4 + w;
    if (r >= N) return;

    float a0 = 0.f, a1 = 0.f;
    if (lane < 20) { float2 bb = *(const float2*)(b2 + 2 * fl); a0 = bb.x; a1 = bb.y; }

    int j = rowptr[r];
    const int end = rowptr[r + 1];
    for (; j + 5 < end; j += 6) {
        const int2 ea = se[j + s];
        const int2 eb = se[j + 3 + s];
        const unsigned ua = hw2[(size_t)ea.x * 20 + fl];
        const unsigned ub = hw2[(size_t)eb.x * 20 + fl];
        const float wa = __int_as_float(ea.y), wb = __int_as_float(eb.y);
        a0 = fmaf(wa, bflo(ua), a0); a1 = fmaf(wa, bfhi(ua), a1);
        a0 = fmaf(wb, bflo(ub), a0); a1 = fmaf(wb, bfhi(ub), a1);
    }
    for (; j < end; j += 3) {
        const int idx = j + s;
        const int ic  = idx < end ? idx : end - 1;
        const int2 e  = se[ic];
        const float wt = idx < end ? __int_as_float(e.y) : 0.f;
        const unsigned u = hw2[(size_t)e.x * 20 + fl];
        a0 = fmaf(wt, bflo(u), a0); a1 = fmaf(wt, bfhi(u), a1);
    }
    const float t0 = __shfl(a0, lane + 20);
    const float t1 = __shfl(a1, lane + 20);
    const float u0 = __shfl(a0, lane + 40);
    const float u1 = __shfl(a1, lane + 40);
    if (lane < 20)
        *(float2*)(out + (size_t)r * 40 + 2 * fl) = make_float2(a0 + t0 + u0, a1 + t1 + u1);
}

extern "C" void kernel_launch(void* const* d_in, const int* in_sizes, int n_in,
                              void* d_out, int out_size, void* d_ws, size_t ws_size,
                              hipStream_t stream)
{
    const float* x  = (const float*)d_in[0];
    const int* erow = (const int*)d_in[1];
    const int* ecol = (const int*)d_in[2];
    const float* ew = (const float*)d_in[3];
    const float* w1 = (const float*)d_in[4];
    const float* b1 = (const float*)d_in[5];
    const float* w2 = (const float*)d_in[6];
    const float* b2 = (const float*)d_in[7];
    float* out = (float*)d_out;

    const int N = in_sizes[0] / 512;   // 50000
    const int E = in_sizes[1];         // 800000
    const int NB = (N + 255) / 256;    // 196 (<=256 for scan2)

    // workspace layout (16B-aligned segments)
    short* w1ts = (short*)d_ws;                      // 128*512 bf16 (swizzled)
    short* w2ts = w1ts + 65536;                      // 48*128 bf16 (swizzled, +pad)
    short* xb   = w2ts + 8192;                       // N*512 bf16 (converted X)
    short* xw1b = xb + (size_t)N * 512;              // N*128 bf16
    short* hb   = xw1b + (size_t)N * 128;            // N*128 bf16 (relu'd)
    int* rowptr = (int*)(hb + (size_t)N * 128);      // N+1
    int* cur    = rowptr + (N + 1);                  // N
    int* bsum   = cur + N;                           // 256 (+pad to 8B align)
    int2* se    = (int2*)(bsum + 256 + ((N + 1) & 1)); // E packed edges
    short* hw2b = xw1b;                              // N*40 bf16 (reuse)

    // prep (weights + zero cur), X->bf16, CSR build
    prep_kernel<<<(65536 + 6144 + N + 255) / 256, 256, 0, stream>>>(w1, w1ts, w2, w2ts, cur, N);
    xconv_kernel<<<2048, 256, 0, stream>>>((const float4*)x, (uint4*)xb, N * 64);
    hist_kernel<<<(E + 255) / 256, 256, 0, stream>>>(erow, cur, E);
    scan1_kernel<<<NB, 256, 0, stream>>>(cur, rowptr, bsum, N);
    scan2_kernel<<<1, 256, 0, stream>>>(bsum, NB);
    scan3_kernel<<<NB, 256, 0, stream>>>(rowptr, bsum, cur, N, E);
    sortedges_kernel<<<(E + 255) / 256, 256, 0, stream>>>(erow, ecol, ew, cur, se, E);

    // layer 1
    const int nwg = (N + 127) / 128;
    gemm1_mfma_kernel<<<nwg, 512, 0, stream>>>(xb, w1ts, xw1b, N, nwg);
    segment1_kernel<<<(N + 3) / 4, 256, 0, stream>>>(rowptr, se,
                                                     (const uint2*)xw1b, b1,
                                                     (uint2*)hb, N);

    // layer 2
    gemm2_mfma_kernel<<<(N + 63) / 64, 256, 0, stream>>>(hb, w2ts,
                                                         (unsigned short*)hw2b, N);
    segment2_kernel<<<(N + 3) / 4, 256, 0, stream>>>(rowptr, se,
                                                     (const unsigned*)hw2b, b2, out, N);
}

// Round 12
// 193.927 us; speedup vs baseline: 1.1184x; 1.1184x over previous
//
#include <hip/hip_runtime.h>
#include <hip/hip_bf16.h>
#include <cstddef>

// GCN forward: out = A·(relu(A·(X·W1)+b1))·W2 + b2
// NFEAT=512, NHID=128, NCLS=40 hard-wired; N,E from in_sizes.
// CSR (counting sort) -> segment-sum SpMM.
// gemm1 (R12): 64x128 tile, BK=32, 15KB single-buffered LDS (padded rows, ~2-way
// free conflicts), reg-staged with load-before-compute, ~6 blocks/CU TLP.

typedef float f32x4 __attribute__((ext_vector_type(4)));
typedef short bf16x8 __attribute__((ext_vector_type(8)));

static __device__ __forceinline__ short f2bf(float f) {
    __hip_bfloat16 b = __float2bfloat16(f);
    return *reinterpret_cast<short*>(&b);
}
static __device__ __forceinline__ float bflo(unsigned u) {
    union { unsigned i; float f; } v; v.i = u << 16; return v.f;
}
static __device__ __forceinline__ float bfhi(unsigned u) {
    union { unsigned i; float f; } v; v.i = u & 0xFFFF0000u; return v.f;
}
static __device__ __forceinline__ unsigned pack2bf(float lo, float hi) {
    unsigned a = (unsigned short)f2bf(lo);
    unsigned b = (unsigned short)f2bf(hi);
    return a | (b << 16);
}

typedef const __attribute__((address_space(1))) void* gas_ptr;
typedef __attribute__((address_space(3))) void* las_ptr;
static __device__ __forceinline__ void gload16(const void* g, void* l) {
    __builtin_amdgcn_global_load_lds((gas_ptr)g, (las_ptr)l, 16, 0, 0);
}

// ---- prep: W1->W1Tb (plain bf16 W1T [128][512]), W2->W2Ts (swizzled), zero cur ----
__global__ __launch_bounds__(256) void prep_kernel(
    const float* __restrict__ W1, short* __restrict__ W1Tb,
    const float* __restrict__ W2, short* __restrict__ W2Ts,
    int* __restrict__ cur, int N)
{
    int idx = blockIdx.x * 256 + threadIdx.x;
    if (idx < 65536) {
        int k = idx >> 7, n = idx & 127;
        W1Tb[n * 512 + k] = f2bf(W1[idx]);
    } else if (idx < 65536 + 6144) {
        int i2 = idx - 65536;
        int n = i2 >> 7, k = i2 & 127;
        W2Ts[i2 ^ ((n & 7) << 3)] = (n < 40) ? f2bf(W2[k * 40 + n]) : (short)0;
    } else if (idx < 65536 + 6144 + N) {
        cur[idx - 65536 - 6144] = 0;
    }
}

// ---------------- GEMM1: XW1b[M,128](bf16) = X[M,512](f32) @ W1 ----------------
// Block 256thr/4 waves, tile 64r x 128c; wave = 32r x 64c (2x4 frags).
// BK=32. As[64][40] bf16 + Bs[128][40] bf16 = 15KB, single-buffered.
// Per tile: (loads issued previous iter) -> bar -> ds_write -> bar -> next loads -> MFMA.
__global__ __launch_bounds__(256, 6) void gemm1_mfma_kernel(
    const float* __restrict__ X, const short* __restrict__ W1Tb,
    short* __restrict__ XW1b, int M)
{
    __shared__ __align__(16) short As[64 * 40];    //  5 KB (rows padded 32->40)
    __shared__ __align__(16) short Bs[128 * 40];   // 10 KB

    const int tid = threadIdx.x;
    const int w   = tid >> 6;
    const int l   = tid & 63;
    const int l15 = l & 15;
    const int l4  = l >> 4;
    const int row0 = blockIdx.x * 64;
    const int rb   = (w & 1) * 32;
    const int cb   = (w >> 1) * 64;

    // staging assignments
    const int sr = tid >> 2;                 // 0..63  A row
    const int sc = (tid & 3) * 8;            // 0,8,16,24 (f32 elems)
    const int ga = row0 + sr < M ? row0 + sr : M - 1;
    const float* ax = X + (size_t)ga * 512 + sc;
    const int bn = tid >> 1;                 // 0..127 B row (= output col)
    const int bk = (tid & 1) * 16;           // 0 or 16 (bf16 elems)
    const short* bw = W1Tb + (size_t)bn * 512 + bk;

    f32x4 acc[2][4];
#pragma unroll
    for (int i = 0; i < 2; ++i)
#pragma unroll
        for (int f = 0; f < 4; ++f) acc[i][f] = (f32x4)0.f;

    // prologue loads (kt = 0)
    float4 a0 = *(const float4*)(ax);
    float4 a1 = *(const float4*)(ax + 4);
    bf16x8 bv0 = *(const bf16x8*)(bw);
    bf16x8 bv1 = *(const bf16x8*)(bw + 8);

#pragma unroll
    for (int kt = 0; kt < 16; ++kt) {
        __syncthreads();                      // previous compute done -> safe to overwrite
        bf16x8 av;
        av[0]=f2bf(a0.x); av[1]=f2bf(a0.y); av[2]=f2bf(a0.z); av[3]=f2bf(a0.w);
        av[4]=f2bf(a1.x); av[5]=f2bf(a1.y); av[6]=f2bf(a1.z); av[7]=f2bf(a1.w);
        *(bf16x8*)&As[sr * 40 + sc] = av;     // sc doubles as bf16 offset (8-elem chunks)
        *(bf16x8*)&Bs[bn * 40 + bk] = bv0;
        *(bf16x8*)&Bs[bn * 40 + bk + 8] = bv1;
        __syncthreads();

        if (kt < 15) {                        // issue next-tile loads BEFORE compute (T3-min)
            a0 = *(const float4*)(ax + (kt + 1) * 32);
            a1 = *(const float4*)(ax + (kt + 1) * 32 + 4);
            bv0 = *(const bf16x8*)(bw + (kt + 1) * 32);
            bv1 = *(const bf16x8*)(bw + (kt + 1) * 32 + 8);
        }

        bf16x8 af0 = *(const bf16x8*)&As[(rb + l15) * 40 + l4 * 8];
        bf16x8 af1 = *(const bf16x8*)&As[(rb + 16 + l15) * 40 + l4 * 8];
#pragma unroll
        for (int f = 0; f < 4; ++f) {
            const bf16x8 bf_ = *(const bf16x8*)&Bs[(cb + f * 16 + l15) * 40 + l4 * 8];
            acc[0][f] = __builtin_amdgcn_mfma_f32_16x16x32_bf16(af0, bf_, acc[0][f], 0, 0, 0);
            acc[1][f] = __builtin_amdgcn_mfma_f32_16x16x32_bf16(af1, bf_, acc[1][f], 0, 0, 0);
        }
    }

    // D layout: col = lane&15, row = (lane>>4)*4 + reg
#pragma unroll
    for (int i = 0; i < 2; ++i)
#pragma unroll
        for (int r = 0; r < 4; ++r) {
            const int row = row0 + rb + i * 16 + l4 * 4 + r;
            if (row < M) {
#pragma unroll
                for (int f = 0; f < 4; ++f)
                    XW1b[(size_t)row * 128 + cb + f * 16 + l15] = f2bf(acc[i][f][r]);
            }
        }
}

// ---------------- CSR build ----------------
__global__ __launch_bounds__(256) void hist_kernel(const int* __restrict__ row,
                                                   int* __restrict__ counts, int E)
{
    int e = blockIdx.x * 256 + threadIdx.x;
    if (e < E) atomicAdd(&counts[row[e]], 1);
}

__global__ __launch_bounds__(256) void scan1_kernel(const int* __restrict__ counts,
                                                    int* __restrict__ excl,
                                                    int* __restrict__ bsum, int N)
{
    __shared__ int s[256];
    const int t = threadIdx.x;
    const int i = blockIdx.x * 256 + t;
    int v = (i < N) ? counts[i] : 0;
    s[t] = v; __syncthreads();
#pragma unroll
    for (int off = 1; off < 256; off <<= 1) {
        int tmp = (t >= off) ? s[t - off] : 0;
        __syncthreads();
        s[t] += tmp;
        __syncthreads();
    }
    if (i < N) excl[i] = s[t] - v;
    if (t == 255) bsum[blockIdx.x] = s[255];
}

__global__ __launch_bounds__(256) void scan2_kernel(int* __restrict__ bsum, int NB)
{
    __shared__ int s[256];
    const int t = threadIdx.x;
    int v = (t < NB) ? bsum[t] : 0;
    s[t] = v; __syncthreads();
#pragma unroll
    for (int off = 1; off < 256; off <<= 1) {
        int tmp = (t >= off) ? s[t - off] : 0;
        __syncthreads();
        s[t] += tmp;
        __syncthreads();
    }
    if (t < NB) bsum[t] = s[t] - v;
}

__global__ __launch_bounds__(256) void scan3_kernel(int* __restrict__ rowptr,
                                                    const int* __restrict__ bsum,
                                                    int* __restrict__ cur, int N, int E)
{
    int i = blockIdx.x * 256 + threadIdx.x;
    if (i < N) {
        int v = rowptr[i] + bsum[blockIdx.x];
        rowptr[i] = v;
        cur[i] = v;
    }
    if (i == 0) rowptr[N] = E;
}

__global__ __launch_bounds__(256) void sortedges_kernel(
    const int* __restrict__ row, const int* __restrict__ col,
    const float* __restrict__ w, int* __restrict__ cur,
    int2* __restrict__ se, int E)
{
    int e = blockIdx.x * 256 + threadIdx.x;
    if (e < E) {
        int r = row[e];
        int pos = atomicAdd(&cur[r], 1);
        se[pos] = make_int2(col[e], __float_as_int(w[e]));
    }
}

// ---- segment1: hb[r] = bf16(relu(b1 + sum_j w_j * xw1b[col_j])) ----
__global__ __launch_bounds__(256) void segment1_kernel(
    const int* __restrict__ rowptr, const int2* __restrict__ se,
    const uint2* __restrict__ x2, const float* __restrict__ b1,
    uint2* __restrict__ hb, int N)
{
    const int w    = threadIdx.x >> 6;
    const int lane = threadIdx.x & 63;
    const int h    = lane >> 5;          // half: which edge of the pair
    const int q    = lane & 31;          // uint2 index in row (feats 4q..4q+3)
    const int r = blockIdx.x * 4 + w;
    if (r >= N) return;

    float4 acc = make_float4(0.f, 0.f, 0.f, 0.f);
    if (h == 0) acc = *(const float4*)(b1 + 4 * q);

    int j = rowptr[r];
    const int end = rowptr[r + 1];
    for (; j + 3 < end; j += 4) {
        const int2 ea = se[j + h];
        const int2 eb = se[j + 2 + h];
        const uint2 ua = x2[(size_t)ea.x * 32 + q];
        const uint2 ub = x2[(size_t)eb.x * 32 + q];
        const float wa = __int_as_float(ea.y), wb = __int_as_float(eb.y);
        acc.x = fmaf(wa, bflo(ua.x), acc.x); acc.y = fmaf(wa, bfhi(ua.x), acc.y);
        acc.z = fmaf(wa, bflo(ua.y), acc.z); acc.w = fmaf(wa, bfhi(ua.y), acc.w);
        acc.x = fmaf(wb, bflo(ub.x), acc.x); acc.y = fmaf(wb, bfhi(ub.x), acc.y);
        acc.z = fmaf(wb, bflo(ub.y), acc.z); acc.w = fmaf(wb, bfhi(ub.y), acc.w);
    }
    for (; j < end; j += 2) {
        const int idx = j + h;
        const int ic  = idx < end ? idx : end - 1;
        const int2 e  = se[ic];
        const float wt = idx < end ? __int_as_float(e.y) : 0.f;
        const uint2 u = x2[(size_t)e.x * 32 + q];
        acc.x = fmaf(wt, bflo(u.x), acc.x); acc.y = fmaf(wt, bfhi(u.x), acc.y);
        acc.z = fmaf(wt, bflo(u.y), acc.z); acc.w = fmaf(wt, bfhi(u.y), acc.w);
    }
    acc.x += __shfl_xor(acc.x, 32);
    acc.y += __shfl_xor(acc.y, 32);
    acc.z += __shfl_xor(acc.z, 32);
    acc.w += __shfl_xor(acc.w, 32);
    if (h == 0) {
        const unsigned p0 = pack2bf(fmaxf(acc.x, 0.f), fmaxf(acc.y, 0.f));
        const unsigned p1 = pack2bf(fmaxf(acc.z, 0.f), fmaxf(acc.w, 0.f));
        hb[(size_t)r * 32 + q] = make_uint2(p0, p1);
    }
}

// ---------------- GEMM2: Yb[M,40](bf16) = hb[M,128](bf16) @ W2 ----------------
__global__ __launch_bounds__(256) void gemm2_mfma_kernel(
    const short* __restrict__ hb, const short* __restrict__ W2Ts,
    unsigned short* __restrict__ Yb, int M)
{
    __shared__ __align__(16) short Ws[48 * 128];   // 12 KB, pre-swizzled

    const int tid = threadIdx.x;
    const int w   = tid >> 6;
    const int l   = tid & 63;
    const int l15 = l & 15;
    const int l4  = l >> 4;
    const int row0 = blockIdx.x * 64 + w * 16;

    {
        const char* src = (const char*)W2Ts;
        char* dst = (char*)Ws;
#pragma unroll
        for (int i = 0; i < 3; ++i)
            gload16(src + i * 4096 + tid * 16, dst + i * 4096 + tid * 16);
    }
    __syncthreads();

    f32x4 acc[3];
#pragma unroll
    for (int f = 0; f < 3; ++f) acc[f] = (f32x4)0.f;

    const int rr = row0 + l15;
    const int cr = rr < M ? rr : M - 1;
    const short* hp = hb + (size_t)cr * 128 + l4 * 8;
    const int swz = (l15 & 7) << 3;

#pragma unroll
    for (int kt = 0; kt < 4; ++kt) {
        const bf16x8 a = *(const bf16x8*)(hp + kt * 32);
#pragma unroll
        for (int f = 0; f < 3; ++f) {
            const int si = ((f * 16 + l15) * 128 + kt * 32 + l4 * 8) ^ swz;
            const bf16x8 b = *(const bf16x8*)&Ws[si];
            acc[f] = __builtin_amdgcn_mfma_f32_16x16x32_bf16(a, b, acc[f], 0, 0, 0);
        }
    }

#pragma unroll
    for (int r = 0; r < 4; ++r) {
        const int row = row0 + l4 * 4 + r;
        if (row < M) {
#pragma unroll
            for (int f = 0; f < 3; ++f) {
                const int col = f * 16 + l15;
                if (col < 40)
                    Yb[(size_t)row * 40 + col] = (unsigned short)f2bf(acc[f][r]);
            }
        }
    }
}

// ---- segment2: out[r] = b2 + sum_j w_j * hw2b[col_j]  (3 edges/wave, x2 unroll) ----
__global__ __launch_bounds__(256) void segment2_kernel(
    const int* __restrict__ rowptr, const int2* __restrict__ se,
    const unsigned* __restrict__ hw2, const float* __restrict__ b2,
    float* __restrict__ out, int N)
{
    const int w    = threadIdx.x >> 6;
    const int lane = threadIdx.x & 63;
    const int s    = lane < 20 ? 0 : (lane < 40 ? 1 : 2);
    const int fl   = lane - s * 20;          // 0..19 (lanes 60-63 discarded)
    const int r = blockIdx.x * 4 + w;
    if (r >= N) return;

    float a0 = 0.f, a1 = 0.f;
    if (lane < 20) { float2 bb = *(const float2*)(b2 + 2 * fl); a0 = bb.x; a1 = bb.y; }

    int j = rowptr[r];
    const int end = rowptr[r + 1];
    for (; j + 5 < end; j += 6) {
        const int2 ea = se[j + s];
        const int2 eb = se[j + 3 + s];
        const unsigned ua = hw2[(size_t)ea.x * 20 + fl];
        const unsigned ub = hw2[(size_t)eb.x * 20 + fl];
        const float wa = __int_as_float(ea.y), wb = __int_as_float(eb.y);
        a0 = fmaf(wa, bflo(ua), a0); a1 = fmaf(wa, bfhi(ua), a1);
        a0 = fmaf(wb, bflo(ub), a0); a1 = fmaf(wb, bfhi(ub), a1);
    }
    for (; j < end; j += 3) {
        const int idx = j + s;
        const int ic  = idx < end ? idx : end - 1;
        const int2 e  = se[ic];
        const float wt = idx < end ? __int_as_float(e.y) : 0.f;
        const unsigned u = hw2[(size_t)e.x * 20 + fl];
        a0 = fmaf(wt, bflo(u), a0); a1 = fmaf(wt, bfhi(u), a1);
    }
    const float t0 = __shfl(a0, lane + 20);
    const float t1 = __shfl(a1, lane + 20);
    const float u0 = __shfl(a0, lane + 40);
    const float u1 = __shfl(a1, lane + 40);
    if (lane < 20)
        *(float2*)(out + (size_t)r * 40 + 2 * fl) = make_float2(a0 + t0 + u0, a1 + t1 + u1);
}

extern "C" void kernel_launch(void* const* d_in, const int* in_sizes, int n_in,
                              void* d_out, int out_size, void* d_ws, size_t ws_size,
                              hipStream_t stream)
{
    const float* x  = (const float*)d_in[0];
    const int* erow = (const int*)d_in[1];
    const int* ecol = (const int*)d_in[2];
    const float* ew = (const float*)d_in[3];
    const float* w1 = (const float*)d_in[4];
    const float* b1 = (const float*)d_in[5];
    const float* w2 = (const float*)d_in[6];
    const float* b2 = (const float*)d_in[7];
    float* out = (float*)d_out;

    const int N = in_sizes[0] / 512;   // 50000
    const int E = in_sizes[1];         // 800000
    const int NB = (N + 255) / 256;    // 196 (<=256 for scan2)

    // workspace layout (16B-aligned segments)
    short* w1tb = (short*)d_ws;                      // 128*512 bf16 (plain W1T)
    short* w2ts = w1tb + 65536;                      // 48*128 bf16 (swizzled, +pad)
    short* xw1b = w2ts + 8192;                       // N*128 bf16
    short* hb   = xw1b + (size_t)N * 128;            // N*128 bf16 (relu'd)
    int* rowptr = (int*)(hb + (size_t)N * 128);      // N+1
    int* cur    = rowptr + (N + 1);                  // N
    int* bsum   = cur + N;                           // 256 (+pad to 8B align)
    int2* se    = (int2*)(bsum + 256 + ((N + 1) & 1)); // E packed edges
    short* hw2b = xw1b;                              // N*40 bf16 (reuse)

    // prep (weights + zero cur) and CSR build
    prep_kernel<<<(65536 + 6144 + N + 255) / 256, 256, 0, stream>>>(w1, w1tb, w2, w2ts, cur, N);
    hist_kernel<<<(E + 255) / 256, 256, 0, stream>>>(erow, cur, E);
    scan1_kernel<<<NB, 256, 0, stream>>>(cur, rowptr, bsum, N);
    scan2_kernel<<<1, 256, 0, stream>>>(bsum, NB);
    scan3_kernel<<<NB, 256, 0, stream>>>(rowptr, bsum, cur, N, E);
    sortedges_kernel<<<(E + 255) / 256, 256, 0, stream>>>(erow, ecol, ew, cur, se, E);

    // layer 1
    gemm1_mfma_kernel<<<(N + 63) / 64, 256, 0, stream>>>(x, w1tb, xw1b, N);
    segment1_kernel<<<(N + 3) / 4, 256, 0, stream>>>(rowptr, se,
                                                     (const uint2*)xw1b, b1,
                                                     (uint2*)hb, N);

    // layer 2
    gemm2_mfma_kernel<<<(N + 63) / 64, 256, 0, stream>>>(hb, w2ts,
                                                         (unsigned short*)hw2b, N);
    segment2_kernel<<<(N + 3) / 4, 256, 0, stream>>>(rowptr, se,
                                                     (const unsigned*)hw2b, b2, out, N);
}

// Round 13
// 189.157 us; speedup vs baseline: 1.1467x; 1.0252x over previous
//
#include <hip/hip_runtime.h>
#include <hip/hip_bf16.h>
#include <cstddef>

// GCN forward: out = A·(relu(A·(X·W1)+b1))·W2 + b2
// NFEAT=512, NHID=128, NCLS=40 hard-wired; N,E from in_sizes.
// CSR (counting sort) -> segment-sum SpMM with quarter-wave gathers
// (4 edges per load instruction, 8 in flight). gemm1: R12 64x128/BK32 winner.

typedef float f32x4 __attribute__((ext_vector_type(4)));
typedef short bf16x8 __attribute__((ext_vector_type(8)));

static __device__ __forceinline__ short f2bf(float f) {
    __hip_bfloat16 b = __float2bfloat16(f);
    return *reinterpret_cast<short*>(&b);
}
static __device__ __forceinline__ float bflo(unsigned u) {
    union { unsigned i; float f; } v; v.i = u << 16; return v.f;
}
static __device__ __forceinline__ float bfhi(unsigned u) {
    union { unsigned i; float f; } v; v.i = u & 0xFFFF0000u; return v.f;
}
static __device__ __forceinline__ unsigned pack2bf(float lo, float hi) {
    unsigned a = (unsigned short)f2bf(lo);
    unsigned b = (unsigned short)f2bf(hi);
    return a | (b << 16);
}

typedef const __attribute__((address_space(1))) void* gas_ptr;
typedef __attribute__((address_space(3))) void* las_ptr;
static __device__ __forceinline__ void gload16(const void* g, void* l) {
    __builtin_amdgcn_global_load_lds((gas_ptr)g, (las_ptr)l, 16, 0, 0);
}

// ---- prep: W1->W1Tb (plain bf16 W1T [128][512]), W2->W2Ts (swizzled), zero cur ----
__global__ __launch_bounds__(256) void prep_kernel(
    const float* __restrict__ W1, short* __restrict__ W1Tb,
    const float* __restrict__ W2, short* __restrict__ W2Ts,
    int* __restrict__ cur, int N)
{
    int idx = blockIdx.x * 256 + threadIdx.x;
    if (idx < 65536) {
        int k = idx >> 7, n = idx & 127;
        W1Tb[n * 512 + k] = f2bf(W1[idx]);
    } else if (idx < 65536 + 6144) {
        int i2 = idx - 65536;
        int n = i2 >> 7, k = i2 & 127;
        W2Ts[i2 ^ ((n & 7) << 3)] = (n < 40) ? f2bf(W2[k * 40 + n]) : (short)0;
    } else if (idx < 65536 + 6144 + N) {
        cur[idx - 65536 - 6144] = 0;
    }
}

// ---------------- GEMM1: XW1b[M,128](bf16) = X[M,512](f32) @ W1 ----------------
// Block 256thr/4 waves, tile 64r x 128c; wave = 32r x 64c (2x4 frags).
// BK=32. As[64][40] bf16 + Bs[128][40] bf16 = 15KB, single-buffered, ~6 blocks/CU.
__global__ __launch_bounds__(256, 6) void gemm1_mfma_kernel(
    const float* __restrict__ X, const short* __restrict__ W1Tb,
    short* __restrict__ XW1b, int M)
{
    __shared__ __align__(16) short As[64 * 40];    //  5 KB (rows padded 32->40)
    __shared__ __align__(16) short Bs[128 * 40];   // 10 KB

    const int tid = threadIdx.x;
    const int w   = tid >> 6;
    const int l   = tid & 63;
    const int l15 = l & 15;
    const int l4  = l >> 4;
    const int row0 = blockIdx.x * 64;
    const int rb   = (w & 1) * 32;
    const int cb   = (w >> 1) * 64;

    const int sr = tid >> 2;
    const int sc = (tid & 3) * 8;
    const int ga = row0 + sr < M ? row0 + sr : M - 1;
    const float* ax = X + (size_t)ga * 512 + sc;
    const int bn = tid >> 1;
    const int bk = (tid & 1) * 16;
    const short* bw = W1Tb + (size_t)bn * 512 + bk;

    f32x4 acc[2][4];
#pragma unroll
    for (int i = 0; i < 2; ++i)
#pragma unroll
        for (int f = 0; f < 4; ++f) acc[i][f] = (f32x4)0.f;

    float4 a0 = *(const float4*)(ax);
    float4 a1 = *(const float4*)(ax + 4);
    bf16x8 bv0 = *(const bf16x8*)(bw);
    bf16x8 bv1 = *(const bf16x8*)(bw + 8);

#pragma unroll
    for (int kt = 0; kt < 16; ++kt) {
        __syncthreads();
        bf16x8 av;
        av[0]=f2bf(a0.x); av[1]=f2bf(a0.y); av[2]=f2bf(a0.z); av[3]=f2bf(a0.w);
        av[4]=f2bf(a1.x); av[5]=f2bf(a1.y); av[6]=f2bf(a1.z); av[7]=f2bf(a1.w);
        *(bf16x8*)&As[sr * 40 + sc] = av;
        *(bf16x8*)&Bs[bn * 40 + bk] = bv0;
        *(bf16x8*)&Bs[bn * 40 + bk + 8] = bv1;
        __syncthreads();

        if (kt < 15) {
            a0 = *(const float4*)(ax + (kt + 1) * 32);
            a1 = *(const float4*)(ax + (kt + 1) * 32 + 4);
            bv0 = *(const bf16x8*)(bw + (kt + 1) * 32);
            bv1 = *(const bf16x8*)(bw + (kt + 1) * 32 + 8);
        }

        bf16x8 af0 = *(const bf16x8*)&As[(rb + l15) * 40 + l4 * 8];
        bf16x8 af1 = *(const bf16x8*)&As[(rb + 16 + l15) * 40 + l4 * 8];
#pragma unroll
        for (int f = 0; f < 4; ++f) {
            const bf16x8 bf_ = *(const bf16x8*)&Bs[(cb + f * 16 + l15) * 40 + l4 * 8];
            acc[0][f] = __builtin_amdgcn_mfma_f32_16x16x32_bf16(af0, bf_, acc[0][f], 0, 0, 0);
            acc[1][f] = __builtin_amdgcn_mfma_f32_16x16x32_bf16(af1, bf_, acc[1][f], 0, 0, 0);
        }
    }

#pragma unroll
    for (int i = 0; i < 2; ++i)
#pragma unroll
        for (int r = 0; r < 4; ++r) {
            const int row = row0 + rb + i * 16 + l4 * 4 + r;
            if (row < M) {
#pragma unroll
                for (int f = 0; f < 4; ++f)
                    XW1b[(size_t)row * 128 + cb + f * 16 + l15] = f2bf(acc[i][f][r]);
            }
        }
}

// ---------------- CSR build ----------------
__global__ __launch_bounds__(256) void hist_kernel(const int* __restrict__ row,
                                                   int* __restrict__ counts, int E)
{
    int e = blockIdx.x * 256 + threadIdx.x;
    if (e < E) atomicAdd(&counts[row[e]], 1);
}

__global__ __launch_bounds__(256) void scan1_kernel(const int* __restrict__ counts,
                                                    int* __restrict__ excl,
                                                    int* __restrict__ bsum, int N)
{
    __shared__ int s[256];
    const int t = threadIdx.x;
    const int i = blockIdx.x * 256 + t;
    int v = (i < N) ? counts[i] : 0;
    s[t] = v; __syncthreads();
#pragma unroll
    for (int off = 1; off < 256; off <<= 1) {
        int tmp = (t >= off) ? s[t - off] : 0;
        __syncthreads();
        s[t] += tmp;
        __syncthreads();
    }
    if (i < N) excl[i] = s[t] - v;
    if (t == 255) bsum[blockIdx.x] = s[255];
}

__global__ __launch_bounds__(256) void scan2_kernel(int* __restrict__ bsum, int NB)
{
    __shared__ int s[256];
    const int t = threadIdx.x;
    int v = (t < NB) ? bsum[t] : 0;
    s[t] = v; __syncthreads();
#pragma unroll
    for (int off = 1; off < 256; off <<= 1) {
        int tmp = (t >= off) ? s[t - off] : 0;
        __syncthreads();
        s[t] += tmp;
        __syncthreads();
    }
    if (t < NB) bsum[t] = s[t] - v;
}

__global__ __launch_bounds__(256) void scan3_kernel(int* __restrict__ rowptr,
                                                    const int* __restrict__ bsum,
                                                    int* __restrict__ cur, int N, int E)
{
    int i = blockIdx.x * 256 + threadIdx.x;
    if (i < N) {
        int v = rowptr[i] + bsum[blockIdx.x];
        rowptr[i] = v;
        cur[i] = v;
    }
    if (i == 0) rowptr[N] = E;
}

__global__ __launch_bounds__(256) void sortedges_kernel(
    const int* __restrict__ row, const int* __restrict__ col,
    const float* __restrict__ w, int* __restrict__ cur,
    int2* __restrict__ se, int E)
{
    int e = blockIdx.x * 256 + threadIdx.x;
    if (e < E) {
        int r = row[e];
        int pos = atomicAdd(&cur[r], 1);
        se[pos] = make_int2(col[e], __float_as_int(w[e]));
    }
}

// ---- segment1: hb[r] = bf16(relu(b1 + sum_j w_j * xw1b[col_j])) ----
// Quarter-wave gathers: 4 edges per uint4-load instruction, x2 unroll (8 in flight).
// lane = qt*16 + ql : qt = edge slot, ql = uint4 index (feats 8ql..8ql+7).
__global__ __launch_bounds__(256) void segment1_kernel(
    const int* __restrict__ rowptr, const int2* __restrict__ se,
    const uint4* __restrict__ x4, const float* __restrict__ b1,
    uint4* __restrict__ hb4, int N)
{
    const int w    = threadIdx.x >> 6;
    const int lane = threadIdx.x & 63;
    const int qt   = lane >> 4;
    const int ql   = lane & 15;
    const int r = blockIdx.x * 4 + w;
    if (r >= N) return;

    float acc[8];
    if (qt == 0) {
        const float4 ba = *(const float4*)(b1 + 8 * ql);
        const float4 bb = *(const float4*)(b1 + 8 * ql + 4);
        acc[0]=ba.x; acc[1]=ba.y; acc[2]=ba.z; acc[3]=ba.w;
        acc[4]=bb.x; acc[5]=bb.y; acc[6]=bb.z; acc[7]=bb.w;
    } else {
#pragma unroll
        for (int i = 0; i < 8; ++i) acc[i] = 0.f;
    }

    int j = rowptr[r];
    const int end = rowptr[r + 1];
    for (; j + 7 < end; j += 8) {
        const int2 ea = se[j + qt];
        const int2 eb = se[j + 4 + qt];
        const uint4 ua = x4[(size_t)ea.x * 16 + ql];
        const uint4 ub = x4[(size_t)eb.x * 16 + ql];
        const float wa = __int_as_float(ea.y), wb = __int_as_float(eb.y);
        acc[0] = fmaf(wa, bflo(ua.x), acc[0]); acc[1] = fmaf(wa, bfhi(ua.x), acc[1]);
        acc[2] = fmaf(wa, bflo(ua.y), acc[2]); acc[3] = fmaf(wa, bfhi(ua.y), acc[3]);
        acc[4] = fmaf(wa, bflo(ua.z), acc[4]); acc[5] = fmaf(wa, bfhi(ua.z), acc[5]);
        acc[6] = fmaf(wa, bflo(ua.w), acc[6]); acc[7] = fmaf(wa, bfhi(ua.w), acc[7]);
        acc[0] = fmaf(wb, bflo(ub.x), acc[0]); acc[1] = fmaf(wb, bfhi(ub.x), acc[1]);
        acc[2] = fmaf(wb, bflo(ub.y), acc[2]); acc[3] = fmaf(wb, bfhi(ub.y), acc[3]);
        acc[4] = fmaf(wb, bflo(ub.z), acc[4]); acc[5] = fmaf(wb, bfhi(ub.z), acc[5]);
        acc[6] = fmaf(wb, bflo(ub.w), acc[6]); acc[7] = fmaf(wb, bfhi(ub.w), acc[7]);
    }
    for (; j < end; j += 4) {
        const int idx = j + qt;
        const int ic  = idx < end ? idx : end - 1;
        const int2 e  = se[ic];
        const float wt = idx < end ? __int_as_float(e.y) : 0.f;
        const uint4 u = x4[(size_t)e.x * 16 + ql];
        acc[0] = fmaf(wt, bflo(u.x), acc[0]); acc[1] = fmaf(wt, bfhi(u.x), acc[1]);
        acc[2] = fmaf(wt, bflo(u.y), acc[2]); acc[3] = fmaf(wt, bfhi(u.y), acc[3]);
        acc[4] = fmaf(wt, bflo(u.z), acc[4]); acc[5] = fmaf(wt, bfhi(u.z), acc[5]);
        acc[6] = fmaf(wt, bflo(u.w), acc[6]); acc[7] = fmaf(wt, bfhi(u.w), acc[7]);
    }
    // reduce across the 4 quarters (xor flips qt bits only; ql preserved)
#pragma unroll
    for (int i = 0; i < 8; ++i) {
        acc[i] += __shfl_xor(acc[i], 16);
        acc[i] += __shfl_xor(acc[i], 32);
    }
    if (qt == 0) {
        uint4 o;
        o.x = pack2bf(fmaxf(acc[0], 0.f), fmaxf(acc[1], 0.f));
        o.y = pack2bf(fmaxf(acc[2], 0.f), fmaxf(acc[3], 0.f));
        o.z = pack2bf(fmaxf(acc[4], 0.f), fmaxf(acc[5], 0.f));
        o.w = pack2bf(fmaxf(acc[6], 0.f), fmaxf(acc[7], 0.f));
        hb4[(size_t)r * 16 + ql] = o;
    }
}

// ---------------- GEMM2: Y48[M,48](bf16) = hb[M,128](bf16) @ W2 ----------------
__global__ __launch_bounds__(256) void gemm2_mfma_kernel(
    const short* __restrict__ hb, const short* __restrict__ W2Ts,
    unsigned short* __restrict__ Y48, int M)
{
    __shared__ __align__(16) short Ws[48 * 128];   // 12 KB, pre-swizzled

    const int tid = threadIdx.x;
    const int w   = tid >> 6;
    const int l   = tid & 63;
    const int l15 = l & 15;
    const int l4  = l >> 4;
    const int row0 = blockIdx.x * 64 + w * 16;

    {
        const char* src = (const char*)W2Ts;
        char* dst = (char*)Ws;
#pragma unroll
        for (int i = 0; i < 3; ++i)
            gload16(src + i * 4096 + tid * 16, dst + i * 4096 + tid * 16);
    }
    __syncthreads();

    f32x4 acc[3];
#pragma unroll
    for (int f = 0; f < 3; ++f) acc[f] = (f32x4)0.f;

    const int rr = row0 + l15;
    const int cr = rr < M ? rr : M - 1;
    const short* hp = hb + (size_t)cr * 128 + l4 * 8;
    const int swz = (l15 & 7) << 3;

#pragma unroll
    for (int kt = 0; kt < 4; ++kt) {
        const bf16x8 a = *(const bf16x8*)(hp + kt * 32);
#pragma unroll
        for (int f = 0; f < 3; ++f) {
            const int si = ((f * 16 + l15) * 128 + kt * 32 + l4 * 8) ^ swz;
            const bf16x8 b = *(const bf16x8*)&Ws[si];
            acc[f] = __builtin_amdgcn_mfma_f32_16x16x32_bf16(a, b, acc[f], 0, 0, 0);
        }
    }

#pragma unroll
    for (int r = 0; r < 4; ++r) {
        const int row = row0 + l4 * 4 + r;
        if (row < M) {
#pragma unroll
            for (int f = 0; f < 3; ++f)
                Y48[(size_t)row * 48 + f * 16 + l15] = (unsigned short)f2bf(acc[f][r]);
        }
    }
}

// ---- segment2: out[r] = b2 + sum_j w_j * h48[col_j]  (quarter-wave, 4 edges/instr) ----
// lane = qt*16 + ql; ql<12 loads uint2 (feats 4ql..4ql+3 of 48-col padded rows).
__global__ __launch_bounds__(256) void segment2_kernel(
    const int* __restrict__ rowptr, const int2* __restrict__ se,
    const uint2* __restrict__ h48, const float* __restrict__ b2,
    float* __restrict__ out, int N)
{
    const int w    = threadIdx.x >> 6;
    const int lane = threadIdx.x & 63;
    const int qt   = lane >> 4;
    const int ql   = lane & 15;
    const int r = blockIdx.x * 4 + w;
    if (r >= N) return;

    float acc[4];
    if (qt == 0 && ql < 10) {
        const float4 bb = *(const float4*)(b2 + 4 * ql);
        acc[0]=bb.x; acc[1]=bb.y; acc[2]=bb.z; acc[3]=bb.w;
    } else {
#pragma unroll
        for (int i = 0; i < 4; ++i) acc[i] = 0.f;
    }

    int j = rowptr[r];
    const int end = rowptr[r + 1];
    for (; j + 7 < end; j += 8) {
        const int2 ea = se[j + qt];
        const int2 eb = se[j + 4 + qt];
        const uint2 ua = h48[(size_t)ea.x * 12 + ql];
        const uint2 ub = h48[(size_t)eb.x * 12 + ql];
        const float wa = __int_as_float(ea.y), wb = __int_as_float(eb.y);
        acc[0] = fmaf(wa, bflo(ua.x), acc[0]); acc[1] = fmaf(wa, bfhi(ua.x), acc[1]);
        acc[2] = fmaf(wa, bflo(ua.y), acc[2]); acc[3] = fmaf(wa, bfhi(ua.y), acc[3]);
        acc[0] = fmaf(wb, bflo(ub.x), acc[0]); acc[1] = fmaf(wb, bfhi(ub.x), acc[1]);
        acc[2] = fmaf(wb, bflo(ub.y), acc[2]); acc[3] = fmaf(wb, bfhi(ub.y), acc[3]);
    }
    for (; j < end; j += 4) {
        const int idx = j + qt;
        const int ic  = idx < end ? idx : end - 1;
        const int2 e  = se[ic];
        const float wt = idx < end ? __int_as_float(e.y) : 0.f;
        const uint2 u = h48[(size_t)e.x * 12 + ql];
        acc[0] = fmaf(wt, bflo(u.x), acc[0]); acc[1] = fmaf(wt, bfhi(u.x), acc[1]);
        acc[2] = fmaf(wt, bflo(u.y), acc[2]); acc[3] = fmaf(wt, bfhi(u.y), acc[3]);
    }
#pragma unroll
    for (int i = 0; i < 4; ++i) {
        acc[i] += __shfl_xor(acc[i], 16);
        acc[i] += __shfl_xor(acc[i], 32);
    }
    if (qt == 0 && ql < 10) {
        float4 o; o.x = acc[0]; o.y = acc[1]; o.z = acc[2]; o.w = acc[3];
        *(float4*)(out + (size_t)r * 40 + 4 * ql) = o;
    }
}

extern "C" void kernel_launch(void* const* d_in, const int* in_sizes, int n_in,
                              void* d_out, int out_size, void* d_ws, size_t ws_size,
                              hipStream_t stream)
{
    const float* x  = (const float*)d_in[0];
    const int* erow = (const int*)d_in[1];
    const int* ecol = (const int*)d_in[2];
    const float* ew = (const float*)d_in[3];
    const float* w1 = (const float*)d_in[4];
    const float* b1 = (const float*)d_in[5];
    const float* w2 = (const float*)d_in[6];
    const float* b2 = (const float*)d_in[7];
    float* out = (float*)d_out;

    const int N = in_sizes[0] / 512;   // 50000
    const int E = in_sizes[1];         // 800000
    const int NB = (N + 255) / 256;    // 196 (<=256 for scan2)

    // workspace layout (16B-aligned segments)
    short* w1tb = (short*)d_ws;                      // 128*512 bf16 (plain W1T)
    short* w2ts = w1tb + 65536;                      // 48*128 bf16 (swizzled)
    short* xw1b = w2ts + 8192;                       // N*128 bf16
    short* hb   = xw1b + (size_t)N * 128;            // N*128 bf16 (relu'd)
    int* rowptr = (int*)(hb + (size_t)N * 128);      // N+1
    int* cur    = rowptr + (N + 1);                  // N
    int* bsum   = cur + N;                           // 256 (+pad to 8B align)
    int2* se    = (int2*)(bsum + 256 + ((N + 1) & 1)); // E packed edges
    short* h48  = xw1b;                              // N*48 bf16 (reuse xw1b)

    // prep (weights + zero cur) and CSR build
    prep_kernel<<<(65536 + 6144 + N + 255) / 256, 256, 0, stream>>>(w1, w1tb, w2, w2ts, cur, N);
    hist_kernel<<<(E + 255) / 256, 256, 0, stream>>>(erow, cur, E);
    scan1_kernel<<<NB, 256, 0, stream>>>(cur, rowptr, bsum, N);
    scan2_kernel<<<1, 256, 0, stream>>>(bsum, NB);
    scan3_kernel<<<NB, 256, 0, stream>>>(rowptr, bsum, cur, N, E);
    sortedges_kernel<<<(E + 255) / 256, 256, 0, stream>>>(erow, ecol, ew, cur, se, E);

    // layer 1
    gemm1_mfma_kernel<<<(N + 63) / 64, 256, 0, stream>>>(x, w1tb, xw1b, N);
    segment1_kernel<<<(N + 3) / 4, 256, 0, stream>>>(rowptr, se,
                                                     (const uint4*)xw1b, b1,
                                                     (uint4*)hb, N);

    // layer 2
    gemm2_mfma_kernel<<<(N + 63) / 64, 256, 0, stream>>>(hb, w2ts,
                                                         (unsigned short*)h48, N);
    segment2_kernel<<<(N + 3) / 4, 256, 0, stream>>>(rowptr, se,
                                                     (const uint2*)h48, b2, out, N);
}

// Round 14
// 155.487 us; speedup vs baseline: 1.3950x; 1.2165x over previous
//
#include <hip/hip_runtime.h>
#include <hip/hip_bf16.h>
#include <cstddef>

// GCN forward: out = A·(relu(A·(X·W1)+b1))·W2 + b2
// NFEAT=512, NHID=128, NCLS=40 hard-wired; N,E from in_sizes.
// R14: 7 launches. sortedges+gemm1 merged (independent, overlap);
// gemm2 fused into segment1 (LDS h rows -> 12 MFMA tail, writes h48 directly);
// scan2+scan3 merged (per-block redundant LDS scan of block sums).

typedef float f32x4 __attribute__((ext_vector_type(4)));
typedef short bf16x8 __attribute__((ext_vector_type(8)));

static __device__ __forceinline__ short f2bf(float f) {
    __hip_bfloat16 b = __float2bfloat16(f);
    return *reinterpret_cast<short*>(&b);
}
static __device__ __forceinline__ float bflo(unsigned u) {
    union { unsigned i; float f; } v; v.i = u << 16; return v.f;
}
static __device__ __forceinline__ float bfhi(unsigned u) {
    union { unsigned i; float f; } v; v.i = u & 0xFFFF0000u; return v.f;
}
static __device__ __forceinline__ unsigned pack2bf(float lo, float hi) {
    unsigned a = (unsigned short)f2bf(lo);
    unsigned b = (unsigned short)f2bf(hi);
    return a | (b << 16);
}

typedef const __attribute__((address_space(1))) void* gas_ptr;
typedef __attribute__((address_space(3))) void* las_ptr;
static __device__ __forceinline__ void gload16(const void* g, void* l) {
    __builtin_amdgcn_global_load_lds((gas_ptr)g, (las_ptr)l, 16, 0, 0);
}

// ---- prep: W1->W1Tb (plain bf16 W1T [128][512]), W2->W2Ts (swizzled), zero cur ----
__global__ __launch_bounds__(256) void prep_kernel(
    const float* __restrict__ W1, short* __restrict__ W1Tb,
    const float* __restrict__ W2, short* __restrict__ W2Ts,
    int* __restrict__ cur, int N)
{
    int idx = blockIdx.x * 256 + threadIdx.x;
    if (idx < 65536) {
        int k = idx >> 7, n = idx & 127;
        W1Tb[n * 512 + k] = f2bf(W1[idx]);
    } else if (idx < 65536 + 6144) {
        int i2 = idx - 65536;
        int n = i2 >> 7, k = i2 & 127;
        W2Ts[i2 ^ ((n & 7) << 3)] = (n < 40) ? f2bf(W2[k * 40 + n]) : (short)0;
    } else if (idx < 65536 + 6144 + N) {
        cur[idx - 65536 - 6144] = 0;
    }
}

// ---------------- CSR build ----------------
__global__ __launch_bounds__(256) void hist_kernel(const int* __restrict__ row,
                                                   int* __restrict__ counts, int E)
{
    int e = blockIdx.x * 256 + threadIdx.x;
    if (e < E) atomicAdd(&counts[row[e]], 1);
}

__global__ __launch_bounds__(256) void scan1_kernel(const int* __restrict__ counts,
                                                    int* __restrict__ excl,
                                                    int* __restrict__ bsum, int N)
{
    __shared__ int s[256];
    const int t = threadIdx.x;
    const int i = blockIdx.x * 256 + t;
    int v = (i < N) ? counts[i] : 0;
    s[t] = v; __syncthreads();
#pragma unroll
    for (int off = 1; off < 256; off <<= 1) {
        int tmp = (t >= off) ? s[t - off] : 0;
        __syncthreads();
        s[t] += tmp;
        __syncthreads();
    }
    if (i < N) excl[i] = s[t] - v;
    if (t == 255) bsum[blockIdx.x] = s[255];
}

// merged scan2+scan3: each block scans bsum in LDS, applies its own prefix
__global__ __launch_bounds__(256) void scan23_kernel(int* __restrict__ rowptr,
                                                     const int* __restrict__ bsum,
                                                     int* __restrict__ cur,
                                                     int N, int E, int NB)
{
    __shared__ int s[256];
    const int t = threadIdx.x;
    int v = (t < NB) ? bsum[t] : 0;
    s[t] = v; __syncthreads();
#pragma unroll
    for (int off = 1; off < 256; off <<= 1) {
        int tmp = (t >= off) ? s[t - off] : 0;
        __syncthreads();
        s[t] += tmp;
        __syncthreads();
    }
    const int add = (blockIdx.x > 0) ? s[blockIdx.x - 1] : 0;  // exclusive prefix
    const int i = blockIdx.x * 256 + t;
    if (i < N) {
        int v2 = rowptr[i] + add;
        rowptr[i] = v2;
        cur[i] = v2;
    }
    if (i == 0) rowptr[N] = E;
}

// ---------------- merged: gemm1 (blocks [0,G1)) + sortedges (blocks [G1,..)) ----------------
// gemm1: XW1b[M,128](bf16) = X[M,512](f32) @ W1. 64x128 tile, BK=32, 15KB LDS.
__global__ __launch_bounds__(256, 6) void gemm1_sort_kernel(
    const float* __restrict__ X, const short* __restrict__ W1Tb,
    short* __restrict__ XW1b, int M, int G1,
    const int* __restrict__ erow, const int* __restrict__ ecol,
    const float* __restrict__ ew, int* __restrict__ cur,
    int2* __restrict__ se, int E)
{
    __shared__ __align__(16) short As[64 * 40];
    __shared__ __align__(16) short Bs[128 * 40];

    const int tid = threadIdx.x;

    if (blockIdx.x >= G1) {
        // ---- sortedges body ----
        int e = (blockIdx.x - G1) * 256 + tid;
        if (e < E) {
            int r = erow[e];
            int pos = atomicAdd(&cur[r], 1);
            se[pos] = make_int2(ecol[e], __float_as_int(ew[e]));
        }
        return;
    }

    // ---- gemm1 body ----
    const int w   = tid >> 6;
    const int l   = tid & 63;
    const int l15 = l & 15;
    const int l4  = l >> 4;
    const int row0 = blockIdx.x * 64;
    const int rb   = (w & 1) * 32;
    const int cb   = (w >> 1) * 64;

    const int sr = tid >> 2;
    const int sc = (tid & 3) * 8;
    const int ga = row0 + sr < M ? row0 + sr : M - 1;
    const float* ax = X + (size_t)ga * 512 + sc;
    const int bn = tid >> 1;
    const int bk = (tid & 1) * 16;
    const short* bw = W1Tb + (size_t)bn * 512 + bk;

    f32x4 acc[2][4];
#pragma unroll
    for (int i = 0; i < 2; ++i)
#pragma unroll
        for (int f = 0; f < 4; ++f) acc[i][f] = (f32x4)0.f;

    float4 a0 = *(const float4*)(ax);
    float4 a1 = *(const float4*)(ax + 4);
    bf16x8 bv0 = *(const bf16x8*)(bw);
    bf16x8 bv1 = *(const bf16x8*)(bw + 8);

#pragma unroll
    for (int kt = 0; kt < 16; ++kt) {
        __syncthreads();
        bf16x8 av;
        av[0]=f2bf(a0.x); av[1]=f2bf(a0.y); av[2]=f2bf(a0.z); av[3]=f2bf(a0.w);
        av[4]=f2bf(a1.x); av[5]=f2bf(a1.y); av[6]=f2bf(a1.z); av[7]=f2bf(a1.w);
        *(bf16x8*)&As[sr * 40 + sc] = av;
        *(bf16x8*)&Bs[bn * 40 + bk] = bv0;
        *(bf16x8*)&Bs[bn * 40 + bk + 8] = bv1;
        __syncthreads();

        if (kt < 15) {
            a0 = *(const float4*)(ax + (kt + 1) * 32);
            a1 = *(const float4*)(ax + (kt + 1) * 32 + 4);
            bv0 = *(const bf16x8*)(bw + (kt + 1) * 32);
            bv1 = *(const bf16x8*)(bw + (kt + 1) * 32 + 8);
        }

        bf16x8 af0 = *(const bf16x8*)&As[(rb + l15) * 40 + l4 * 8];
        bf16x8 af1 = *(const bf16x8*)&As[(rb + 16 + l15) * 40 + l4 * 8];
#pragma unroll
        for (int f = 0; f < 4; ++f) {
            const bf16x8 bf_ = *(const bf16x8*)&Bs[(cb + f * 16 + l15) * 40 + l4 * 8];
            acc[0][f] = __builtin_amdgcn_mfma_f32_16x16x32_bf16(af0, bf_, acc[0][f], 0, 0, 0);
            acc[1][f] = __builtin_amdgcn_mfma_f32_16x16x32_bf16(af1, bf_, acc[1][f], 0, 0, 0);
        }
    }

#pragma unroll
    for (int i = 0; i < 2; ++i)
#pragma unroll
        for (int r = 0; r < 4; ++r) {
            const int row = row0 + rb + i * 16 + l4 * 4 + r;
            if (row < M) {
#pragma unroll
                for (int f = 0; f < 4; ++f)
                    XW1b[(size_t)row * 128 + cb + f * 16 + l15] = f2bf(acc[i][f][r]);
            }
        }
}

// ---- fused segment1+gemm2: h48[r] = bf16(relu(b1 + Σ w_j xw1b[col_j])) @ W2 ----
// Gather: quarter-wave (4 edges/instr, x2 unroll). Tail: h rows -> LDS, 12 MFMA.
__global__ __launch_bounds__(256) void seg1g2_kernel(
    const int* __restrict__ rowptr, const int2* __restrict__ se,
    const uint4* __restrict__ x4, const float* __restrict__ b1,
    const short* __restrict__ W2Ts, unsigned short* __restrict__ h48, int N)
{
    __shared__ __align__(16) short Ws[48 * 128];   // 12 KB, pre-swizzled
    __shared__ __align__(16) short Hs[16 * 136];   // 4.25 KB, pitch 136 (2-way free)

    const int tid  = threadIdx.x;
    const int w    = tid >> 6;
    const int lane = tid & 63;
    const int qt   = lane >> 4;
    const int ql   = lane & 15;
    const int row0q = blockIdx.x * 4;
    const int r  = row0q + w;
    const int rc = r < N ? r : N - 1;     // clamp: all waves reach the barrier

    // stage W2 into LDS (async; drained by the barrier below)
    {
        const char* src = (const char*)W2Ts;
        char* dst = (char*)Ws;
#pragma unroll
        for (int i = 0; i < 3; ++i)
            gload16(src + i * 4096 + tid * 16, dst + i * 4096 + tid * 16);
    }

    float acc[8];
    if (qt == 0) {
        const float4 ba = *(const float4*)(b1 + 8 * ql);
        const float4 bb = *(const float4*)(b1 + 8 * ql + 4);
        acc[0]=ba.x; acc[1]=ba.y; acc[2]=ba.z; acc[3]=ba.w;
        acc[4]=bb.x; acc[5]=bb.y; acc[6]=bb.z; acc[7]=bb.w;
    } else {
#pragma unroll
        for (int i = 0; i < 8; ++i) acc[i] = 0.f;
    }

    int j = rowptr[rc];
    const int end = rowptr[rc + 1];
    for (; j + 7 < end; j += 8) {
        const int2 ea = se[j + qt];
        const int2 eb = se[j + 4 + qt];
        const uint4 ua = x4[(size_t)ea.x * 16 + ql];
        const uint4 ub = x4[(size_t)eb.x * 16 + ql];
        const float wa = __int_as_float(ea.y), wb = __int_as_float(eb.y);
        acc[0] = fmaf(wa, bflo(ua.x), acc[0]); acc[1] = fmaf(wa, bfhi(ua.x), acc[1]);
        acc[2] = fmaf(wa, bflo(ua.y), acc[2]); acc[3] = fmaf(wa, bfhi(ua.y), acc[3]);
        acc[4] = fmaf(wa, bflo(ua.z), acc[4]); acc[5] = fmaf(wa, bfhi(ua.z), acc[5]);
        acc[6] = fmaf(wa, bflo(ua.w), acc[6]); acc[7] = fmaf(wa, bfhi(ua.w), acc[7]);
        acc[0] = fmaf(wb, bflo(ub.x), acc[0]); acc[1] = fmaf(wb, bfhi(ub.x), acc[1]);
        acc[2] = fmaf(wb, bflo(ub.y), acc[2]); acc[3] = fmaf(wb, bfhi(ub.y), acc[3]);
        acc[4] = fmaf(wb, bflo(ub.z), acc[4]); acc[5] = fmaf(wb, bfhi(ub.z), acc[5]);
        acc[6] = fmaf(wb, bflo(ub.w), acc[6]); acc[7] = fmaf(wb, bfhi(ub.w), acc[7]);
    }
    for (; j < end; j += 4) {
        const int idx = j + qt;
        const int ic  = idx < end ? idx : end - 1;
        const int2 e  = se[ic];
        const float wt = idx < end ? __int_as_float(e.y) : 0.f;
        const uint4 u = x4[(size_t)e.x * 16 + ql];
        acc[0] = fmaf(wt, bflo(u.x), acc[0]); acc[1] = fmaf(wt, bfhi(u.x), acc[1]);
        acc[2] = fmaf(wt, bflo(u.y), acc[2]); acc[3] = fmaf(wt, bfhi(u.y), acc[3]);
        acc[4] = fmaf(wt, bflo(u.z), acc[4]); acc[5] = fmaf(wt, bfhi(u.z), acc[5]);
        acc[6] = fmaf(wt, bflo(u.w), acc[6]); acc[7] = fmaf(wt, bfhi(u.w), acc[7]);
    }
#pragma unroll
    for (int i = 0; i < 8; ++i) {
        acc[i] += __shfl_xor(acc[i], 16);
        acc[i] += __shfl_xor(acc[i], 32);
    }
    if (qt == 0) {
        uint4 o;
        o.x = pack2bf(fmaxf(acc[0], 0.f), fmaxf(acc[1], 0.f));
        o.y = pack2bf(fmaxf(acc[2], 0.f), fmaxf(acc[3], 0.f));
        o.z = pack2bf(fmaxf(acc[4], 0.f), fmaxf(acc[5], 0.f));
        o.w = pack2bf(fmaxf(acc[6], 0.f), fmaxf(acc[7], 0.f));
        *(uint4*)&Hs[w * 136 + ql * 8] = o;   // h row w (relu'd bf16)
    }
    __syncthreads();   // drains gload16 (vmcnt) + Hs writes

    // MFMA tail on wave 0: D[16,48] = Hs[16,128] @ W2; rows 4..15 garbage, discarded.
    if (tid < 64) {
        const int l15 = lane & 15;
        const int l4  = lane >> 4;
        const int swz = (l15 & 7) << 3;
        f32x4 acc2[3];
#pragma unroll
        for (int f = 0; f < 3; ++f) acc2[f] = (f32x4)0.f;
#pragma unroll
        for (int kt = 0; kt < 4; ++kt) {
            const bf16x8 a = *(const bf16x8*)&Hs[l15 * 136 + kt * 32 + l4 * 8];
#pragma unroll
            for (int f = 0; f < 3; ++f) {
                const int si = ((f * 16 + l15) * 128 + kt * 32 + l4 * 8) ^ swz;
                const bf16x8 b = *(const bf16x8*)&Ws[si];
                acc2[f] = __builtin_amdgcn_mfma_f32_16x16x32_bf16(a, b, acc2[f], 0, 0, 0);
            }
        }
        if (l4 == 0) {     // D rows 0..3 live in lanes 0..15, regs 0..3
#pragma unroll
            for (int rr = 0; rr < 4; ++rr) {
                const int grow = row0q + rr;
                if (grow < N) {
#pragma unroll
                    for (int f = 0; f < 3; ++f)
                        h48[(size_t)grow * 48 + f * 16 + l15] =
                            (unsigned short)f2bf(acc2[f][rr]);
                }
            }
        }
    }
}

// ---- segment2: out[r] = b2 + sum_j w_j * h48[col_j]  (quarter-wave, 4 edges/instr) ----
__global__ __launch_bounds__(256) void segment2_kernel(
    const int* __restrict__ rowptr, const int2* __restrict__ se,
    const uint2* __restrict__ h48, const float* __restrict__ b2,
    float* __restrict__ out, int N)
{
    const int w    = threadIdx.x >> 6;
    const int lane = threadIdx.x & 63;
    const int qt   = lane >> 4;
    const int ql   = lane & 15;
    const int r = blockIdx.x * 4 + w;
    if (r >= N) return;

    float acc[4];
    if (qt == 0 && ql < 10) {
        const float4 bb = *(const float4*)(b2 + 4 * ql);
        acc[0]=bb.x; acc[1]=bb.y; acc[2]=bb.z; acc[3]=bb.w;
    } else {
#pragma unroll
        for (int i = 0; i < 4; ++i) acc[i] = 0.f;
    }

    int j = rowptr[r];
    const int end = rowptr[r + 1];
    for (; j + 7 < end; j += 8) {
        const int2 ea = se[j + qt];
        const int2 eb = se[j + 4 + qt];
        const uint2 ua = h48[(size_t)ea.x * 12 + ql];
        const uint2 ub = h48[(size_t)eb.x * 12 + ql];
        const float wa = __int_as_float(ea.y), wb = __int_as_float(eb.y);
        acc[0] = fmaf(wa, bflo(ua.x), acc[0]); acc[1] = fmaf(wa, bfhi(ua.x), acc[1]);
        acc[2] = fmaf(wa, bflo(ua.y), acc[2]); acc[3] = fmaf(wa, bfhi(ua.y), acc[3]);
        acc[0] = fmaf(wb, bflo(ub.x), acc[0]); acc[1] = fmaf(wb, bfhi(ub.x), acc[1]);
        acc[2] = fmaf(wb, bflo(ub.y), acc[2]); acc[3] = fmaf(wb, bfhi(ub.y), acc[3]);
    }
    for (; j < end; j += 4) {
        const int idx = j + qt;
        const int ic  = idx < end ? idx : end - 1;
        const int2 e  = se[ic];
        const float wt = idx < end ? __int_as_float(e.y) : 0.f;
        const uint2 u = h48[(size_t)e.x * 12 + ql];
        acc[0] = fmaf(wt, bflo(u.x), acc[0]); acc[1] = fmaf(wt, bfhi(u.x), acc[1]);
        acc[2] = fmaf(wt, bflo(u.y), acc[2]); acc[3] = fmaf(wt, bfhi(u.y), acc[3]);
    }
#pragma unroll
    for (int i = 0; i < 4; ++i) {
        acc[i] += __shfl_xor(acc[i], 16);
        acc[i] += __shfl_xor(acc[i], 32);
    }
    if (qt == 0 && ql < 10) {
        float4 o; o.x = acc[0]; o.y = acc[1]; o.z = acc[2]; o.w = acc[3];
        *(float4*)(out + (size_t)r * 40 + 4 * ql) = o;
    }
}

extern "C" void kernel_launch(void* const* d_in, const int* in_sizes, int n_in,
                              void* d_out, int out_size, void* d_ws, size_t ws_size,
                              hipStream_t stream)
{
    const float* x  = (const float*)d_in[0];
    const int* erow = (const int*)d_in[1];
    const int* ecol = (const int*)d_in[2];
    const float* ew = (const float*)d_in[3];
    const float* w1 = (const float*)d_in[4];
    const float* b1 = (const float*)d_in[5];
    const float* w2 = (const float*)d_in[6];
    const float* b2 = (const float*)d_in[7];
    float* out = (float*)d_out;

    const int N = in_sizes[0] / 512;   // 50000
    const int E = in_sizes[1];         // 800000
    const int NB = (N + 255) / 256;    // 196 (<=256 for scan23)

    // workspace layout (16B-aligned segments)
    short* w1tb = (short*)d_ws;                      // 128*512 bf16 (plain W1T)
    short* w2ts = w1tb + 65536;                      // 48*128 bf16 (swizzled)
    short* xw1b = w2ts + 8192;                       // N*128 bf16 (gather table L1)
    short* h48  = xw1b + (size_t)N * 128;            // N*48 bf16 (gather table L2)
    int* rowptr = (int*)(h48 + (size_t)N * 128);     // N+1 (h48 slot padded to N*128)
    int* cur    = rowptr + (N + 1);                  // N
    int* bsum   = cur + N;                           // 256 (+pad to 8B align)
    int2* se    = (int2*)(bsum + 256 + ((N + 1) & 1)); // E packed edges

    // CSR build + weight prep
    prep_kernel<<<(65536 + 6144 + N + 255) / 256, 256, 0, stream>>>(w1, w1tb, w2, w2ts, cur, N);
    hist_kernel<<<(E + 255) / 256, 256, 0, stream>>>(erow, cur, E);
    scan1_kernel<<<NB, 256, 0, stream>>>(cur, rowptr, bsum, N);
    scan23_kernel<<<NB, 256, 0, stream>>>(rowptr, bsum, cur, N, E, NB);

    // gemm1 + sortedges (independent, merged)
    const int G1 = (N + 63) / 64;
    const int GS = (E + 255) / 256;
    gemm1_sort_kernel<<<G1 + GS, 256, 0, stream>>>(x, w1tb, xw1b, N, G1,
                                                   erow, ecol, ew, cur, se, E);

    // layer 1 aggregate + layer 2 GEMM (fused)
    seg1g2_kernel<<<(N + 3) / 4, 256, 0, stream>>>(rowptr, se,
                                                   (const uint4*)xw1b, b1,
                                                   w2ts, (unsigned short*)h48, N);

    // layer 2 aggregate
    segment2_kernel<<<(N + 3) / 4, 256, 0, stream>>>(rowptr, se,
                                                     (const uint2*)h48, b2, out, N);
}